// Round 1
// baseline (75.510 us; speedup 1.0000x reference)
//
#include <hip/hip_runtime.h>

// ---------- types ----------
typedef __attribute__((ext_vector_type(8))) short bf16x8;
typedef __attribute__((ext_vector_type(4))) float f32x4;

__device__ __forceinline__ short f2bf(float f) {
  unsigned u = __builtin_bit_cast(unsigned, f);
  u += 0x7fffu + ((u >> 16) & 1u);   // round-to-nearest-even
  return (short)(u >> 16);
}

// ---------- sizes ----------
// IN=4096, OUT=4096, RANK=1024, GROUP=128, PACK=8
// P  [4096 k][1024 r]  = (dequant V) * S[r]     (bf16)
// Qt [4096 n][1024 r]  = (dequant U)^T          (bf16)
// out[n*4096 + k] = sum_r P[k][r] * Qt[n][r]    (fp32)

// ---------- stage 1a: V dequant (fold S) ----------
// thread t: k = t>>7, r0 = (t&127)*8 ; writes P[k][r0..r0+7]
__global__ __launch_bounds__(256) void dequant_v(const int* __restrict__ qw,
                                                 const int* __restrict__ qz,
                                                 const float* __restrict__ sc,
                                                 const float* __restrict__ S,
                                                 short* __restrict__ P) {
  const int t  = blockIdx.x * 256 + threadIdx.x;
  const int r8 = t & 127;
  const int k  = t >> 7;
  const int g  = k >> 7;            // k / 128
  const int kw = k >> 3;            // qweight row
  const int sh = (k & 7) << 2;      // nibble shift for this k
  const int r0 = r8 << 3;
  const int zw = qz[(g << 7) + r8]; // qzeros_V [32][128], 8 zeros for r0..r0+7
  const int*   wq  = qw + kw * 1024 + r0;
  const float* scp = sc + (g << 10) + r0;
  const float* sp  = S + r0;
  bf16x8 res;
#pragma unroll
  for (int i = 0; i < 8; ++i) {
    int q = (wq[i] >> sh) & 15;
    int z = ((zw >> (i << 2)) & 15) + 1;
    res[i] = f2bf((float)(q - z) * scp[i] * sp[i]);
  }
  *(bf16x8*)(P + (k << 10) + r0) = res;
}

// ---------- stage 1b: U dequant, transposed output ----------
// thread t: n = t>>7, rw = t&127 (word row, r0 = rw*8); writes Qt[n][r0..r0+7]
__global__ __launch_bounds__(256) void dequant_u(const int* __restrict__ qw,
                                                 const int* __restrict__ qz,
                                                 const float* __restrict__ sc,
                                                 short* __restrict__ Qt) {
  const int t  = blockIdx.x * 256 + threadIdx.x;
  const int rw = t & 127;
  const int n  = t >> 7;
  const int g  = rw >> 4;           // (rw*8)/128
  const int w  = qw[(rw << 12) + n];             // qweight_U [128][4096]
  const int zw = qz[(g << 9) + (n >> 3)];        // qzeros_U  [8][512]
  const int z  = ((zw >> ((n & 7) << 2)) & 15) + 1;
  const float s = sc[(g << 12) + n];             // scales_U  [8][4096]
  bf16x8 res;
#pragma unroll
  for (int i = 0; i < 8; ++i) {
    int q = (w >> (i << 2)) & 15;
    res[i] = f2bf((float)(q - z) * s);
  }
  *(bf16x8*)(Qt + (n << 10) + (rw << 3)) = res;
}

// ---------- stage 2: bf16 MFMA GEMM (m97 structure) ----------
// 128x128 tile, BK=32, 4 waves (each 64x64 = 4x4 fragments of 16x16x32).
// As/Bs both [128 rows][32 k] row-major, staged via global_load_lds width=16.
#define GLL(g, l)                                                              \
  __builtin_amdgcn_global_load_lds(                                            \
      (const __attribute__((address_space(1))) void*)(g),                      \
      (__attribute__((address_space(3))) void*)(l), 16, 0, 0)

__global__ __launch_bounds__(256) void gemm_kernel(const short* __restrict__ P,
                                                   const short* __restrict__ Qt,
                                                   float* __restrict__ out) {
  __shared__ __align__(16) short As[128 * 32];
  __shared__ __align__(16) short Bs[128 * 32];
  const int tid  = threadIdx.x;
  const int lane = tid & 63;
  const int w    = tid >> 6;
  const int tm = blockIdx.x >> 5;
  const int tn = blockIdx.x & 31;
  const int m0 = tm << 7, n0 = tn << 7;
  const int m_off = (w >> 1) << 6;   // wave sub-tile 64x64
  const int n_off = (w & 1) << 6;

  // staging: 8 chunks of 64 lanes x 16B per matrix; wave w does chunks {w, w+4}
  const int flat0 = (w << 6) + lane;
  const int flat1 = ((w + 4) << 6) + lane;
  const short* gA0 = P  + (m0 + (flat0 >> 2)) * 1024 + ((flat0 & 3) << 3);
  const short* gA1 = P  + (m0 + (flat1 >> 2)) * 1024 + ((flat1 & 3) << 3);
  const short* gB0 = Qt + (n0 + (flat0 >> 2)) * 1024 + ((flat0 & 3) << 3);
  const short* gB1 = Qt + (n0 + (flat1 >> 2)) * 1024 + ((flat1 & 3) << 3);
  short* lA0 = As + (w << 9);
  short* lA1 = As + ((w + 4) << 9);
  short* lB0 = Bs + (w << 9);
  short* lB1 = Bs + ((w + 4) << 9);

  f32x4 acc[4][4];
#pragma unroll
  for (int i = 0; i < 4; ++i)
#pragma unroll
    for (int j = 0; j < 4; ++j) acc[i][j] = f32x4{0.f, 0.f, 0.f, 0.f};

  // fragment read addresses: lane holds row (lane&15), k = 8*(lane>>4)..+7
  const short* ap = As + (m_off + (lane & 15)) * 32 + ((lane >> 4) << 3);
  const short* bp = Bs + (n_off + (lane & 15)) * 32 + ((lane >> 4) << 3);

  for (int kt = 0; kt < 32; ++kt) {
    const int kb = kt << 5;
    GLL(gA0 + kb, lA0);
    GLL(gA1 + kb, lA1);
    GLL(gB0 + kb, lB0);
    GLL(gB1 + kb, lB1);
    __syncthreads();                 // drains vmcnt, publishes LDS
    bf16x8 a[4], b[4];
#pragma unroll
    for (int i = 0; i < 4; ++i) {
      a[i] = *(const bf16x8*)(ap + (i << 9));   // +i*16 rows * 32
      b[i] = *(const bf16x8*)(bp + (i << 9));
    }
#pragma unroll
    for (int i = 0; i < 4; ++i)
#pragma unroll
      for (int j = 0; j < 4; ++j)
        acc[i][j] = __builtin_amdgcn_mfma_f32_16x16x32_bf16(a[i], b[j], acc[i][j], 0, 0, 0);
    __syncthreads();                 // protect LDS before next stage
  }

  // epilogue: out[n*4096 + m]; D reg j -> m consecutive -> float4 store
  const int mb = m0 + m_off + ((lane >> 4) << 2);
  const int nb = n0 + n_off + (lane & 15);
#pragma unroll
  for (int i = 0; i < 4; ++i)
#pragma unroll
    for (int j = 0; j < 4; ++j) {
      float* o = out + (nb + (j << 4)) * 4096 + mb + (i << 4);
      *(f32x4*)o = acc[i][j];
    }
}

// ---------- launcher ----------
// setup_inputs order: 0:x 1:qweight_V 2:qzeros_V 3:scales_V 4:g_idx_V
//                     5:qweight_U 6:qzeros_U 7:scales_U 8:g_idx_U 9:S
extern "C" void kernel_launch(void* const* d_in, const int* in_sizes, int n_in,
                              void* d_out, int out_size, void* d_ws, size_t ws_size,
                              hipStream_t stream) {
  const int*   qw_V = (const int*)d_in[1];
  const int*   qz_V = (const int*)d_in[2];
  const float* sc_V = (const float*)d_in[3];
  const int*   qw_U = (const int*)d_in[5];
  const int*   qz_U = (const int*)d_in[6];
  const float* sc_U = (const float*)d_in[7];
  const float* S    = (const float*)d_in[9];

  short* P  = (short*)d_ws;                  // 4096*1024 bf16 = 8 MB
  short* Qt = (short*)d_ws + 4096 * 1024;    // 4096*1024 bf16 = 8 MB
  float* out = (float*)d_out;

  dequant_v<<<2048, 256, 0, stream>>>(qw_V, qz_V, sc_V, S, P);
  dequant_u<<<2048, 256, 0, stream>>>(qw_U, qz_U, sc_U, Qt);
  gemm_kernel<<<1024, 256, 0, stream>>>(P, Qt, out);
}

// Round 2
// 57.929 us; speedup vs baseline: 1.3035x; 1.3035x over previous
//
#include <hip/hip_runtime.h>

// ---------- types ----------
typedef __attribute__((ext_vector_type(8))) short bf16x8;
typedef __attribute__((ext_vector_type(4))) float f32x4;

__device__ __forceinline__ short f2bf(float f) {
  unsigned u = __builtin_bit_cast(unsigned, f);
  u += 0x7fffu + ((u >> 16) & 1u);   // round-to-nearest-even
  return (short)(u >> 16);
}

// ---------- sizes ----------
// IN=4096, OUT=4096, RANK=1024, GROUP=128, PACK=8
// P  [4096 k][1024 r]  = (dequant V) * S[r]     (bf16)
// Qt [4096 n][1024 r]  = (dequant U)^T          (bf16)
// out[n*4096 + k] = sum_r P[k][r] * Qt[n][r]    (fp32)

// ---------- stage 1a: V dequant (fold S) ----------
__global__ __launch_bounds__(256) void dequant_v(const int* __restrict__ qw,
                                                 const int* __restrict__ qz,
                                                 const float* __restrict__ sc,
                                                 const float* __restrict__ S,
                                                 short* __restrict__ P) {
  const int t  = blockIdx.x * 256 + threadIdx.x;
  const int r8 = t & 127;
  const int k  = t >> 7;
  const int g  = k >> 7;
  const int kw = k >> 3;
  const int sh = (k & 7) << 2;
  const int r0 = r8 << 3;
  const int zw = qz[(g << 7) + r8];
  const int*   wq  = qw + kw * 1024 + r0;
  const float* scp = sc + (g << 10) + r0;
  const float* sp  = S + r0;
  bf16x8 res;
#pragma unroll
  for (int i = 0; i < 8; ++i) {
    int q = (wq[i] >> sh) & 15;
    int z = ((zw >> (i << 2)) & 15) + 1;
    res[i] = f2bf((float)(q - z) * scp[i] * sp[i]);
  }
  *(bf16x8*)(P + (k << 10) + r0) = res;
}

// ---------- stage 1b: U dequant, transposed output ----------
__global__ __launch_bounds__(256) void dequant_u(const int* __restrict__ qw,
                                                 const int* __restrict__ qz,
                                                 const float* __restrict__ sc,
                                                 short* __restrict__ Qt) {
  const int t  = blockIdx.x * 256 + threadIdx.x;
  const int rw = t & 127;
  const int n  = t >> 7;
  const int g  = rw >> 4;
  const int w  = qw[(rw << 12) + n];
  const int zw = qz[(g << 9) + (n >> 3)];
  const int z  = ((zw >> ((n & 7) << 2)) & 15) + 1;
  const float s = sc[(g << 12) + n];
  bf16x8 res;
#pragma unroll
  for (int i = 0; i < 8; ++i) {
    int q = (w >> (i << 2)) & 15;
    res[i] = f2bf((float)(q - z) * s);
  }
  *(bf16x8*)(Qt + (n << 10) + (rw << 3)) = res;
}

// ---------- stage 2: 256x256-tile BK=64 GEMM, counted-vmcnt pipeline ----------
// 8 waves (2M x 4N), per-wave output 128x64 = acc[8][4] f32x4.
// LDS 128 KiB: buf b at b*65536: A [256r][64k] swizzled at +0, B at +32768.
// Swizzle: physical byte = row*128 + (logicalcol ^ ((row&7)<<4)); GLL dest is
// linear, so the global SOURCE is pre-swizzled with the same involution.
#define GLL(g, l)                                                              \
  __builtin_amdgcn_global_load_lds(                                            \
      (const __attribute__((address_space(1))) void*)(g),                      \
      (__attribute__((address_space(3))) void*)(l), 16, 0, 0)

__global__ __launch_bounds__(512, 2) void gemm256(const short* __restrict__ P,
                                                  const short* __restrict__ Qt,
                                                  float* __restrict__ out) {
  __shared__ __align__(16) char lds[131072];
  const int tid  = threadIdx.x;          // 0..511
  const int lane = tid & 63;
  const int wid  = tid >> 6;             // 0..7
  const int wm   = wid >> 2;             // 0..1
  const int wn   = wid & 3;              // 0..3
  const int m0 = (blockIdx.x >> 4) << 8;
  const int n0 = (blockIdx.x & 15) << 8;

  // staging sources: round r covers rows r*64+ (tid>>3), 16B at swizzled col
  const int srow = tid >> 3;                                  // 0..63
  const int scol = ((tid & 7) << 4) ^ ((srow & 7) << 4);      // byte, 16B-aligned
  const short* pA[4];
  const short* pB[4];
#pragma unroll
  for (int r = 0; r < 4; ++r) {
    pA[r] = P  + (m0 + r * 64 + srow) * 1024 + (scol >> 1);
    pB[r] = Qt + (n0 + r * 64 + srow) * 1024 + (scol >> 1);
  }

#define STAGE(b, kt) do {                                                      \
    const int kb_ = (kt) << 6;                                                 \
    _Pragma("unroll")                                                          \
    for (int r_ = 0; r_ < 4; ++r_)                                             \
      GLL(pA[r_] + kb_, lds + (b) * 65536 + r_ * 8192 + wid * 1024);           \
    _Pragma("unroll")                                                          \
    for (int r_ = 0; r_ < 4; ++r_)                                             \
      GLL(pB[r_] + kb_, lds + (b) * 65536 + 32768 + r_ * 8192 + wid * 1024);   \
  } while (0)

  // fragment read offsets (bytes within A/B region)
  const int ra   = ((wm << 7) + (lane & 15)) << 7;   // (wm*128 + row)*128
  const int rb   = ((wn << 6) + (lane & 15)) << 7;   // (wn*64  + row)*128
  const int swz  = (lane & 7) << 4;
  const int offk0 = (((lane >> 4) << 4)) ^ swz;
  const int offk1 = (64 + ((lane >> 4) << 4)) ^ swz;

  f32x4 acc[8][4];
#pragma unroll
  for (int mi = 0; mi < 8; ++mi)
#pragma unroll
    for (int ni = 0; ni < 4; ++ni) acc[mi][ni] = f32x4{0.f, 0.f, 0.f, 0.f};

  // prologue: 2 K-tiles in flight
  STAGE(0, 0);
  STAGE(1, 1);

  int cur = 0;
  for (int kt = 0; kt < 16; ++kt) {
    // my 8 oldest GLLs (this buffer's stage) must have landed; keep the next
    // tile's 8 in flight (counted vmcnt — never 0 until the tail).
    if (kt == 15) asm volatile("s_waitcnt vmcnt(0)" ::: "memory");
    else          asm volatile("s_waitcnt vmcnt(8)" ::: "memory");
    __builtin_amdgcn_s_barrier();        // whole tile now visible to all waves
    __builtin_amdgcn_sched_barrier(0);   // pin: no ds_read hoisted above

    const char* Ab = lds + cur * 65536;
    const char* Bb = Ab + 32768;
#pragma unroll
    for (int kk = 0; kk < 2; ++kk) {
      const int offk = kk ? offk1 : offk0;
      bf16x8 bfr[4], afr[8];
#pragma unroll
      for (int ni = 0; ni < 4; ++ni)
        bfr[ni] = *(const bf16x8*)(Bb + rb + ni * 2048 + offk);
#pragma unroll
      for (int mi = 0; mi < 8; ++mi)
        afr[mi] = *(const bf16x8*)(Ab + ra + mi * 2048 + offk);
      __builtin_amdgcn_s_setprio(1);
#pragma unroll
      for (int mi = 0; mi < 8; ++mi)
#pragma unroll
        for (int ni = 0; ni < 4; ++ni)
          acc[mi][ni] = __builtin_amdgcn_mfma_f32_16x16x32_bf16(
              afr[mi], bfr[ni], acc[mi][ni], 0, 0, 0);
      __builtin_amdgcn_s_setprio(0);
    }

    asm volatile("s_waitcnt lgkmcnt(0)" ::: "memory");  // my reads of buf done
    __builtin_amdgcn_s_barrier();        // all waves done reading buf[cur]
    if (kt < 14) STAGE(cur, kt + 2);     // safe to overwrite now
    cur ^= 1;
  }

  // epilogue: out[n*4096 + m]; 4 acc regs = consecutive m -> float4 store
  const int mbase = m0 + (wm << 7) + ((lane >> 4) << 2);
  const int nbase = n0 + (wn << 6) + (lane & 15);
#pragma unroll
  for (int mi = 0; mi < 8; ++mi)
#pragma unroll
    for (int ni = 0; ni < 4; ++ni)
      *(f32x4*)(out + (size_t)(nbase + ni * 16) * 4096 + mbase + mi * 16) =
          acc[mi][ni];
#undef STAGE
}

// ---------- launcher ----------
// setup_inputs order: 0:x 1:qweight_V 2:qzeros_V 3:scales_V 4:g_idx_V
//                     5:qweight_U 6:qzeros_U 7:scales_U 8:g_idx_U 9:S
extern "C" void kernel_launch(void* const* d_in, const int* in_sizes, int n_in,
                              void* d_out, int out_size, void* d_ws, size_t ws_size,
                              hipStream_t stream) {
  const int*   qw_V = (const int*)d_in[1];
  const int*   qz_V = (const int*)d_in[2];
  const float* sc_V = (const float*)d_in[3];
  const int*   qw_U = (const int*)d_in[5];
  const int*   qz_U = (const int*)d_in[6];
  const float* sc_U = (const float*)d_in[7];
  const float* S    = (const float*)d_in[9];

  short* P  = (short*)d_ws;                  // 4096*1024 bf16 = 8 MB
  short* Qt = (short*)d_ws + 4096 * 1024;    // 4096*1024 bf16 = 8 MB
  float* out = (float*)d_out;

  dequant_v<<<2048, 256, 0, stream>>>(qw_V, qz_V, sc_V, S, P);
  dequant_u<<<2048, 256, 0, stream>>>(qw_U, qz_U, sc_U, Qt);
  gemm256<<<256, 512, 0, stream>>>(P, Qt, out);
}

// Round 4
// 55.047 us; speedup vs baseline: 1.3717x; 1.0523x over previous
//
#include <hip/hip_runtime.h>

// ---------- types ----------
typedef __attribute__((ext_vector_type(8))) short bf16x8;
typedef __attribute__((ext_vector_type(4))) float f32x4;

__device__ __forceinline__ short f2bf(float f) {
  unsigned u = __builtin_bit_cast(unsigned, f);
  u += 0x7fffu + ((u >> 16) & 1u);   // round-to-nearest-even
  return (short)(u >> 16);
}

// ---------- sizes ----------
// IN=4096, OUT=4096, RANK=1024, GROUP=128, PACK=8
// P  [4096 k][1024 r]  = (dequant V) * S[r]     (bf16)
// Qt [4096 n][1024 r]  = (dequant U)^T          (bf16)
// out[n*4096 + k] = sum_r P[k][r] * Qt[n][r]    (fp32)

// ---------- stage 1a: V dequant (fold S) ----------
__global__ __launch_bounds__(256) void dequant_v(const int* __restrict__ qw,
                                                 const int* __restrict__ qz,
                                                 const float* __restrict__ sc,
                                                 const float* __restrict__ S,
                                                 short* __restrict__ P) {
  const int t  = blockIdx.x * 256 + threadIdx.x;
  const int r8 = t & 127;
  const int k  = t >> 7;
  const int g  = k >> 7;
  const int kw = k >> 3;
  const int sh = (k & 7) << 2;
  const int r0 = r8 << 3;
  const int zw = qz[(g << 7) + r8];
  const int*   wq  = qw + kw * 1024 + r0;
  const float* scp = sc + (g << 10) + r0;
  const float* sp  = S + r0;
  bf16x8 res;
#pragma unroll
  for (int i = 0; i < 8; ++i) {
    int q = (wq[i] >> sh) & 15;
    int z = ((zw >> (i << 2)) & 15) + 1;
    res[i] = f2bf((float)(q - z) * scp[i] * sp[i]);
  }
  *(bf16x8*)(P + (k << 10) + r0) = res;
}

// ---------- stage 1b: U dequant, transposed output ----------
__global__ __launch_bounds__(256) void dequant_u(const int* __restrict__ qw,
                                                 const int* __restrict__ qz,
                                                 const float* __restrict__ sc,
                                                 short* __restrict__ Qt) {
  const int t  = blockIdx.x * 256 + threadIdx.x;
  const int rw = t & 127;
  const int n  = t >> 7;
  const int g  = rw >> 4;
  const int w  = qw[(rw << 12) + n];
  const int zw = qz[(g << 9) + (n >> 3)];
  const int z  = ((zw >> ((n & 7) << 2)) & 15) + 1;
  const float s = sc[(g << 12) + n];
  bf16x8 res;
#pragma unroll
  for (int i = 0; i < 8; ++i) {
    int q = (w >> (i << 2)) & 15;
    res[i] = f2bf((float)(q - z) * s);
  }
  *(bf16x8*)(Qt + (n << 10) + (rw << 3)) = res;
}

// ---------- stage 2: 256x256, BK=64, 8-wave, 4-phase/K-tile ----------
// LDS: buf b at b*65536; A region [256r][64k] at +0, B at +32768.
// Swizzle (both-sides involution): phys byte = row*128 + (col ^ ((row&7)<<4)).
// GLL dest linear -> global SOURCE col pre-swizzled; ds_read re-applies XOR.
//
// Read pattern (per iteration, waves split by wm/wn):
//   A staging half 0 (rows 0..127):  read in ph0 AND ph2 by wm=0 waves
//   A staging half 1 (rows 128..255):read in ph0 AND ph2 by wm=1 waves
//   B halves: read in ph0 AND ph1.
// => B(kt+2) may be staged in ph2 (after ph1 barrier);
//    A(kt+2) may be staged in ph3 (after ph2 barrier).   [R3's race: A in ph1]
// vmcnt ledger: 8 outstanding entering each iter (tile kt+1); ph2 +4, ph3 +4;
// end-of-ph3 vmcnt(8) retires exactly tile kt+1's 8. kt==14 -> vmcnt(0).
#define GLL(g, l)                                                              \
  __builtin_amdgcn_global_load_lds(                                            \
      (const __attribute__((address_space(1))) void*)(g),                      \
      (__attribute__((address_space(3))) void*)(l), 16, 0, 0)

__global__ __launch_bounds__(512, 2) void gemm256(const short* __restrict__ P,
                                                  const short* __restrict__ Qt,
                                                  float* __restrict__ out) {
  __shared__ __align__(16) char lds[131072];
  const int tid  = threadIdx.x;          // 0..511
  const int lane = tid & 63;
  const int wid  = tid >> 6;             // 0..7
  const int wm   = wid >> 2;             // 0..1
  const int wn   = wid & 3;              // 0..3
  const int m0 = (blockIdx.x >> 4) << 8;
  const int n0 = (blockIdx.x & 15) << 8;

  // staging: thread -> row tid>>3 (0..63), 16B chunk tid&7 (pre-swizzled col)
  const int srow = tid >> 3;
  const int scol = ((tid & 7) << 4) ^ ((srow & 7) << 4);
  const short* gA = P  + (m0 + srow) * 1024 + (scol >> 1);
  const short* gB = Qt + (n0 + srow) * 1024 + (scol >> 1);

  // STG(gp, region_byte_off, half, ktarget): one 128-row half-tile (2 GLL)
#define STG(gp, roff, half, ktv) do {                                          \
    const short* s_ = (gp) + (half) * 131072 + ((ktv) << 6);                   \
    char* d_ = lds + (roff) + (half) * 16384 + (wid << 10);                    \
    GLL(s_, d_);                                                               \
    GLL(s_ + 65536, d_ + 8192);                                                \
  } while (0)

  // fragment read addressing
  const int arow_b = ((wm << 7) + (lane & 15)) << 7;   // (wm*128+row)*128 bytes
  const int brow_b = ((wn << 6) + (lane & 15)) << 7;   // (wn*64 +row)*128 bytes
  const int klo  = (lane >> 4) << 4;
  const int swz  = (lane & 7) << 4;
  const int offk0 = klo ^ swz;
  const int offk1 = (klo | 64) ^ swz;

  f32x4 acc[8][4];
#pragma unroll
  for (int mi = 0; mi < 8; ++mi)
#pragma unroll
    for (int ni = 0; ni < 4; ++ni) acc[mi][ni] = f32x4{0.f, 0.f, 0.f, 0.f};

  bf16x8 ah[4][2], bh0[2][2], bh1[2][2];

  // ---- prologue: tiles 0 and 1 fully staged (16 GLL) ----
  STG(gA, 0, 0, 0);              // A-h0(0)
  STG(gA, 0, 1, 0);              // A-h1(0)
  STG(gB, 32768, 0, 0);          // B-h0(0)
  STG(gB, 32768, 1, 0);          // B-h1(0)
  STG(gA, 65536, 0, 1);          // A-h0(1)
  STG(gA, 65536, 1, 1);          // A-h1(1)
  STG(gB, 65536 + 32768, 0, 1);  // B-h0(1)
  STG(gB, 65536 + 32768, 1, 1);  // B-h1(1)
  asm volatile("s_waitcnt vmcnt(8)" ::: "memory");   // tile 0 fully landed
  __builtin_amdgcn_s_barrier();

  for (int kt = 0; kt < 16; ++kt) {
    const int curbuf = (kt & 1) << 16;        // buffer of kt (and kt+2)
    const char* Ab = lds + curbuf;
    const char* Bb = Ab + 32768;

    // ---------- phase 0: Q(m0,n0) — read wave's A rows 0..63 + B cols 0..31 --
#pragma unroll
    for (int i = 0; i < 4; ++i) {
      ah[i][0] = *(const bf16x8*)(Ab + arow_b + i * 2048 + offk0);
      ah[i][1] = *(const bf16x8*)(Ab + arow_b + i * 2048 + offk1);
    }
#pragma unroll
    for (int j = 0; j < 2; ++j) {
      bh0[j][0] = *(const bf16x8*)(Bb + brow_b + j * 2048 + offk0);
      bh0[j][1] = *(const bf16x8*)(Bb + brow_b + j * 2048 + offk1);
    }
    asm volatile("s_waitcnt lgkmcnt(0)" ::: "memory");
    __builtin_amdgcn_sched_barrier(0);
    __builtin_amdgcn_s_setprio(1);
#pragma unroll
    for (int kk = 0; kk < 2; ++kk)
#pragma unroll
      for (int i = 0; i < 4; ++i)
#pragma unroll
        for (int j = 0; j < 2; ++j)
          acc[i][j] = __builtin_amdgcn_mfma_f32_16x16x32_bf16(
              ah[i][kk], bh0[j][kk], acc[i][j], 0, 0, 0);
    __builtin_amdgcn_s_setprio(0);
    __builtin_amdgcn_s_barrier();

    // ---------- phase 1: Q(m0,n1) — read B cols 32..63 ----------
#pragma unroll
    for (int j = 0; j < 2; ++j) {
      bh1[j][0] = *(const bf16x8*)(Bb + brow_b + 4096 + j * 2048 + offk0);
      bh1[j][1] = *(const bf16x8*)(Bb + brow_b + 4096 + j * 2048 + offk1);
    }
    asm volatile("s_waitcnt lgkmcnt(0)" ::: "memory");
    __builtin_amdgcn_sched_barrier(0);
    __builtin_amdgcn_s_setprio(1);
#pragma unroll
    for (int kk = 0; kk < 2; ++kk)
#pragma unroll
      for (int i = 0; i < 4; ++i)
#pragma unroll
        for (int j = 0; j < 2; ++j)
          acc[i][2 + j] = __builtin_amdgcn_mfma_f32_16x16x32_bf16(
              ah[i][kk], bh1[j][kk], acc[i][2 + j], 0, 0, 0);
    __builtin_amdgcn_s_setprio(0);
    __builtin_amdgcn_s_barrier();          // all B reads of tile kt complete

    // ---------- phase 2: Q(m1,n1) — read A rows 64..127; stage B(kt+2) ------
#pragma unroll
    for (int i = 0; i < 4; ++i) {
      ah[i][0] = *(const bf16x8*)(Ab + arow_b + 8192 + i * 2048 + offk0);
      ah[i][1] = *(const bf16x8*)(Ab + arow_b + 8192 + i * 2048 + offk1);
    }
    if (kt < 14) {
      STG(gB, curbuf + 32768, 0, kt + 2);
      STG(gB, curbuf + 32768, 1, kt + 2);
    }
    asm volatile("s_waitcnt lgkmcnt(0)" ::: "memory");
    __builtin_amdgcn_sched_barrier(0);
    __builtin_amdgcn_s_setprio(1);
#pragma unroll
    for (int kk = 0; kk < 2; ++kk)
#pragma unroll
      for (int i = 0; i < 4; ++i)
#pragma unroll
        for (int j = 0; j < 2; ++j)
          acc[4 + i][2 + j] = __builtin_amdgcn_mfma_f32_16x16x32_bf16(
              ah[i][kk], bh1[j][kk], acc[4 + i][2 + j], 0, 0, 0);
    __builtin_amdgcn_s_setprio(0);
    __builtin_amdgcn_s_barrier();          // all A reads of tile kt complete

    // ---------- phase 3: Q(m1,n0) — regs held; stage A(kt+2) ----------
    if (kt < 14) {
      STG(gA, curbuf, 0, kt + 2);
      STG(gA, curbuf, 1, kt + 2);
    }
    __builtin_amdgcn_s_setprio(1);
#pragma unroll
    for (int kk = 0; kk < 2; ++kk)
#pragma unroll
      for (int i = 0; i < 4; ++i)
#pragma unroll
        for (int j = 0; j < 2; ++j)
          acc[4 + i][j] = __builtin_amdgcn_mfma_f32_16x16x32_bf16(
              ah[i][kk], bh0[j][kk], acc[4 + i][j], 0, 0, 0);
    __builtin_amdgcn_s_setprio(0);
    // counted vmcnt: retire tile kt+1's 8 GLLs, keep tile kt+2's 8 in flight
    if (kt == 14) asm volatile("s_waitcnt vmcnt(0)" ::: "memory");
    else          asm volatile("s_waitcnt vmcnt(8)" ::: "memory");
    __builtin_amdgcn_s_barrier();
  }

  // epilogue: out[n*4096 + m]; 4 acc regs = consecutive m -> float4 store
  const int mbase = m0 + (wm << 7) + ((lane >> 4) << 2);
  const int nbase = n0 + (wn << 6) + (lane & 15);
#pragma unroll
  for (int mi = 0; mi < 8; ++mi)
#pragma unroll
    for (int ni = 0; ni < 4; ++ni)
      *(f32x4*)(out + (size_t)(nbase + ni * 16) * 4096 + mbase + mi * 16) =
          acc[mi][ni];
#undef STG
}

// ---------- launcher ----------
// setup_inputs order: 0:x 1:qweight_V 2:qzeros_V 3:scales_V 4:g_idx_V
//                     5:qweight_U 6:qzeros_U 7:scales_U 8:g_idx_U 9:S
extern "C" void kernel_launch(void* const* d_in, const int* in_sizes, int n_in,
                              void* d_out, int out_size, void* d_ws, size_t ws_size,
                              hipStream_t stream) {
  const int*   qw_V = (const int*)d_in[1];
  const int*   qz_V = (const int*)d_in[2];
  const float* sc_V = (const float*)d_in[3];
  const int*   qw_U = (const int*)d_in[5];
  const int*   qz_U = (const int*)d_in[6];
  const float* sc_U = (const float*)d_in[7];
  const float* S    = (const float*)d_in[9];

  short* P  = (short*)d_ws;                  // 4096*1024 bf16 = 8 MB
  short* Qt = (short*)d_ws + 4096 * 1024;    // 4096*1024 bf16 = 8 MB
  float* out = (float*)d_out;

  dequant_v<<<2048, 256, 0, stream>>>(qw_V, qz_V, sc_V, S, P);
  dequant_u<<<2048, 256, 0, stream>>>(qw_U, qz_U, sc_U, Qt);
  gemm256<<<256, 512, 0, stream>>>(P, Qt, out);
}

// Round 5
// 51.444 us; speedup vs baseline: 1.4678x; 1.0700x over previous
//
#include <hip/hip_runtime.h>

// ---------- types ----------
typedef __attribute__((ext_vector_type(8))) short bf16x8;
typedef __attribute__((ext_vector_type(4))) float f32x4;

__device__ __forceinline__ short f2bf(float f) {
  unsigned u = __builtin_bit_cast(unsigned, f);
  u += 0x7fffu + ((u >> 16) & 1u);   // round-to-nearest-even
  return (short)(u >> 16);
}

// ---------- layout ----------
// IN=4096, OUT=4096, RANK=1024, GROUP=128, PACK=8
// GEMM: out[n*4096+m] = sum_r W_V(m,r)*S(r) * W_U(r,n)
// A = P_re, B = Qt_re, both stored FRAGMENT-MAJOR:
//   element addr = ((panel*16 + kt)*32 + blk)*512 + lane*8 + e
//   A blk = h*16 + i*2 + kk  (h = m-half, i = 16-row frag, kk = 32-k half)
//     m = panel*256 + h*128 + i*16 + (lane&15); r = kt*64 + kk*32 + (lane>>4)*8 + e
//   B blk = q*8 + j*2 + kk   (q = n-quarter, j = 16-col frag)
//     n = panel*256 + q*64 + j*16 + (lane&15);  r = kt*64 + kk*32 + (lane>>4)*8 + e
// => each 1024-B block is one MFMA fragment in lane order: GLL copies it
//    contiguously, ds_read_b128 is stride-1 across lanes (conflict-free).

// ---------- stage 1a: V dequant (fold S), fragment-major output ----------
__global__ __launch_bounds__(256) void dequant_v(const int* __restrict__ qw,
                                                 const int* __restrict__ qz,
                                                 const float* __restrict__ sc,
                                                 const float* __restrict__ S,
                                                 short* __restrict__ A) {
  const int t    = blockIdx.x * 256 + threadIdx.x;   // 0..524287
  const int tile = t >> 11;                          // (panel,kt)
  const int blk  = (t >> 6) & 31;
  const int lane = t & 63;
  const int panel = tile >> 4, kt = tile & 15;
  const int m  = (panel << 8) + (((blk >> 4) & 1) << 7) + (((blk >> 1) & 7) << 4) + (lane & 15);
  const int r0 = (kt << 6) + ((blk & 1) << 5) + ((lane >> 4) << 3);

  const int g  = m >> 7;
  const int sh = (m & 7) << 2;
  const int zw = qz[(g << 7) + (r0 >> 3)];
  const int*   wq  = qw + (m >> 3) * 1024 + r0;
  const float* scp = sc + (g << 10) + r0;
  const float* sp  = S + r0;
  bf16x8 res;
#pragma unroll
  for (int e = 0; e < 8; ++e) {
    int q = (wq[e] >> sh) & 15;
    int z = ((zw >> (e << 2)) & 15) + 1;
    res[e] = f2bf((float)(q - z) * scp[e] * sp[e]);
  }
  *(bf16x8*)(A + ((size_t)t << 3)) = res;            // perfectly coalesced
}

// ---------- stage 1b: U dequant, fragment-major transposed output ----------
__global__ __launch_bounds__(256) void dequant_u(const int* __restrict__ qw,
                                                 const int* __restrict__ qz,
                                                 const float* __restrict__ sc,
                                                 short* __restrict__ B) {
  const int t    = blockIdx.x * 256 + threadIdx.x;
  const int tile = t >> 11;
  const int blk  = (t >> 6) & 31;
  const int lane = t & 63;
  const int panel = tile >> 4, kt = tile & 15;
  const int n  = (panel << 8) + (((blk >> 3) & 3) << 6) + (((blk >> 1) & 3) << 4) + (lane & 15);
  const int r0 = (kt << 6) + ((blk & 1) << 5) + ((lane >> 4) << 3);

  const int w  = qw[(r0 >> 3) * 4096 + n];           // 8 nibbles r0..r0+7
  const int g  = r0 >> 7;
  const int zw = qz[(g << 9) + (n >> 3)];
  const int z  = ((zw >> ((n & 7) << 2)) & 15) + 1;
  const float s = sc[(g << 12) + n];
  bf16x8 res;
#pragma unroll
  for (int e = 0; e < 8; ++e) {
    int q = (w >> (e << 2)) & 15;
    res[e] = f2bf((float)(q - z) * s);
  }
  *(bf16x8*)(B + ((size_t)t << 3)) = res;
}

// ---------- stage 2: 256x256, BK=64, 8-wave, 4-phase/K-tile ----------
// LDS: buf b at b*65536; A blocks 0..31 at +0, B blocks 0..31 at +32768.
// Phase reads: ph0 A(i=0..3)+B(j=0,1); ph1 B(j=2,3); ph2 A(i=4..7); ph3 none.
// Stage: ph2 -> B(kt+2) (B fully read after ph1 barrier);
//        ph3 -> A(kt+2) (A fully read after ph2 barrier).
// vmcnt: enter iter with 8 outstanding (tile kt+1); ph2 +4, ph3 +4;
// end-of-ph3 vmcnt(8) retires tile kt+1's 8. kt==14 -> vmcnt(0).
#define GLL(g, l)                                                              \
  __builtin_amdgcn_global_load_lds(                                            \
      (const __attribute__((address_space(1))) void*)(g),                      \
      (__attribute__((address_space(3))) void*)(l), 16, 0, 0)

__global__ __launch_bounds__(512, 2) void gemm256(const short* __restrict__ A,
                                                  const short* __restrict__ B,
                                                  float* __restrict__ out) {
  __shared__ __align__(16) char lds[131072];
  const int tid  = threadIdx.x;          // 0..511
  const int lane = tid & 63;
  const int wid  = tid >> 6;             // 0..7
  const int wm   = wid >> 2;             // 0..1
  const int wn   = wid & 3;              // 0..3
  const int mp = blockIdx.x >> 4;
  const int np = blockIdx.x & 15;

  // staging: wave wid copies A blocks wid*4..+3 and B blocks wid*4..+3
  const short* gA = A + ((size_t)(mp * 16) << 14) + (wid << 11) + (lane << 3);
  const short* gB = B + ((size_t)(np * 16) << 14) + (wid << 11) + (lane << 3);

#define STGA(buf, ktv) do {                                                    \
    const short* s_ = gA + ((ktv) << 14);                                      \
    char* d_ = lds + (buf) + (wid << 12);                                      \
    GLL(s_,        d_);                                                        \
    GLL(s_ +  512, d_ + 1024);                                                 \
    GLL(s_ + 1024, d_ + 2048);                                                 \
    GLL(s_ + 1536, d_ + 3072);                                                 \
  } while (0)
#define STGB(buf, ktv) do {                                                    \
    const short* s_ = gB + ((ktv) << 14);                                      \
    char* d_ = lds + (buf) + 32768 + (wid << 12);                              \
    GLL(s_,        d_);                                                        \
    GLL(s_ +  512, d_ + 1024);                                                 \
    GLL(s_ + 1024, d_ + 2048);                                                 \
    GLL(s_ + 1536, d_ + 3072);                                                 \
  } while (0)

  // fragment read bases: block (h,i,kk) at h*16384 + (i*2+kk)*1024 + lane*16
  const char* Ard = lds + (wm << 14) + (lane << 4);
  const char* Brd = lds + 32768 + (wn << 13) + (lane << 4);

  f32x4 acc[8][4];
#pragma unroll
  for (int mi = 0; mi < 8; ++mi)
#pragma unroll
    for (int ni = 0; ni < 4; ++ni) acc[mi][ni] = f32x4{0.f, 0.f, 0.f, 0.f};

  bf16x8 ah[4][2], bh0[2][2], bh1[2][2];

  // ---- prologue: tiles 0,1 staged in steady-state FIFO order (B then A) ----
  STGB(0, 0);
  STGA(0, 0);
  STGB(65536, 1);
  STGA(65536, 1);
  asm volatile("s_waitcnt vmcnt(8)" ::: "memory");   // tile 0 fully landed
  __builtin_amdgcn_s_barrier();

  for (int kt = 0; kt < 16; ++kt) {
    const int curbuf = (kt & 1) << 16;   // buffer of tile kt (and kt+2)

    // ---------- phase 0: Q(m0,n0) — A frags i=0..3, B frags j=0,1 ----------
#pragma unroll
    for (int i = 0; i < 4; ++i) {
      ah[i][0] = *(const bf16x8*)(Ard + curbuf + (i << 11));
      ah[i][1] = *(const bf16x8*)(Ard + curbuf + (i << 11) + 1024);
    }
#pragma unroll
    for (int j = 0; j < 2; ++j) {
      bh0[j][0] = *(const bf16x8*)(Brd + curbuf + (j << 11));
      bh0[j][1] = *(const bf16x8*)(Brd + curbuf + (j << 11) + 1024);
    }
    asm volatile("s_waitcnt lgkmcnt(0)" ::: "memory");
    __builtin_amdgcn_sched_barrier(0);
    __builtin_amdgcn_s_setprio(1);
#pragma unroll
    for (int kk = 0; kk < 2; ++kk)
#pragma unroll
      for (int i = 0; i < 4; ++i)
#pragma unroll
        for (int j = 0; j < 2; ++j)
          acc[i][j] = __builtin_amdgcn_mfma_f32_16x16x32_bf16(
              ah[i][kk], bh0[j][kk], acc[i][j], 0, 0, 0);
    __builtin_amdgcn_s_setprio(0);
    __builtin_amdgcn_s_barrier();

    // ---------- phase 1: Q(m0,n1) — B frags j=2,3 ----------
#pragma unroll
    for (int j = 0; j < 2; ++j) {
      bh1[j][0] = *(const bf16x8*)(Brd + curbuf + 4096 + (j << 11));
      bh1[j][1] = *(const bf16x8*)(Brd + curbuf + 4096 + (j << 11) + 1024);
    }
    asm volatile("s_waitcnt lgkmcnt(0)" ::: "memory");
    __builtin_amdgcn_sched_barrier(0);
    __builtin_amdgcn_s_setprio(1);
#pragma unroll
    for (int kk = 0; kk < 2; ++kk)
#pragma unroll
      for (int i = 0; i < 4; ++i)
#pragma unroll
        for (int j = 0; j < 2; ++j)
          acc[i][2 + j] = __builtin_amdgcn_mfma_f32_16x16x32_bf16(
              ah[i][kk], bh1[j][kk], acc[i][2 + j], 0, 0, 0);
    __builtin_amdgcn_s_setprio(0);
    __builtin_amdgcn_s_barrier();          // all B reads of tile kt complete

    // ---------- phase 2: Q(m1,n1) — A frags i=4..7; stage B(kt+2) ----------
#pragma unroll
    for (int i = 0; i < 4; ++i) {
      ah[i][0] = *(const bf16x8*)(Ard + curbuf + 8192 + (i << 11));
      ah[i][1] = *(const bf16x8*)(Ard + curbuf + 8192 + (i << 11) + 1024);
    }
    if (kt < 14) STGB(curbuf, kt + 2);
    asm volatile("s_waitcnt lgkmcnt(0)" ::: "memory");
    __builtin_amdgcn_sched_barrier(0);
    __builtin_amdgcn_s_setprio(1);
#pragma unroll
    for (int kk = 0; kk < 2; ++kk)
#pragma unroll
      for (int i = 0; i < 4; ++i)
#pragma unroll
        for (int j = 0; j < 2; ++j)
          acc[4 + i][2 + j] = __builtin_amdgcn_mfma_f32_16x16x32_bf16(
              ah[i][kk], bh1[j][kk], acc[4 + i][2 + j], 0, 0, 0);
    __builtin_amdgcn_s_setprio(0);
    __builtin_amdgcn_s_barrier();          // all A reads of tile kt complete

    // ---------- phase 3: Q(m1,n0) — regs held; stage A(kt+2) ----------
    if (kt < 14) STGA(curbuf, kt + 2);
    __builtin_amdgcn_s_setprio(1);
#pragma unroll
    for (int kk = 0; kk < 2; ++kk)
#pragma unroll
      for (int i = 0; i < 4; ++i)
#pragma unroll
        for (int j = 0; j < 2; ++j)
          acc[4 + i][j] = __builtin_amdgcn_mfma_f32_16x16x32_bf16(
              ah[i][kk], bh0[j][kk], acc[4 + i][j], 0, 0, 0);
    __builtin_amdgcn_s_setprio(0);
    if (kt == 14) asm volatile("s_waitcnt vmcnt(0)" ::: "memory");
    else          asm volatile("s_waitcnt vmcnt(8)" ::: "memory");
    __builtin_amdgcn_s_barrier();
  }

  // epilogue: out[n*4096 + m]; 4 acc regs = consecutive m -> float4 store
  const int mbase = (mp << 8) + (wm << 7) + ((lane >> 4) << 2);
  const int nbase = (np << 8) + (wn << 6) + (lane & 15);
#pragma unroll
  for (int mi = 0; mi < 8; ++mi)
#pragma unroll
    for (int ni = 0; ni < 4; ++ni)
      *(f32x4*)(out + (size_t)(nbase + ni * 16) * 4096 + mbase + mi * 16) =
          acc[mi][ni];
#undef STGA
#undef STGB
}

// ---------- launcher ----------
// setup_inputs order: 0:x 1:qweight_V 2:qzeros_V 3:scales_V 4:g_idx_V
//                     5:qweight_U 6:qzeros_U 7:scales_U 8:g_idx_U 9:S
extern "C" void kernel_launch(void* const* d_in, const int* in_sizes, int n_in,
                              void* d_out, int out_size, void* d_ws, size_t ws_size,
                              hipStream_t stream) {
  const int*   qw_V = (const int*)d_in[1];
  const int*   qz_V = (const int*)d_in[2];
  const float* sc_V = (const float*)d_in[3];
  const int*   qw_U = (const int*)d_in[5];
  const int*   qz_U = (const int*)d_in[6];
  const float* sc_U = (const float*)d_in[7];
  const float* S    = (const float*)d_in[9];

  short* A = (short*)d_ws;                  // 8 MB fragment-major P
  short* B = (short*)d_ws + 4096 * 1024;    // 8 MB fragment-major Qt
  float* out = (float*)d_out;

  dequant_v<<<2048, 256, 0, stream>>>(qw_V, qz_V, sc_V, S, A);
  dequant_u<<<2048, 256, 0, stream>>>(qw_U, qz_U, sc_U, B);
  gemm256<<<256, 512, 0, stream>>>(A, B, out);
}